// Round 6
// baseline (595.242 us; speedup 1.0000x reference)
//
#include <hip/hip_runtime.h>
#include <hip/hip_bf16.h>
#include <math.h>

#define NUM_EMB 8192
#define DIM 512
#define NROWS 16384   // 32*512
#define NPART 4096    // gather_loss partial sums (one per block)

typedef unsigned short ushort;
typedef unsigned long long ull;
typedef __attribute__((ext_vector_type(8))) short short8;
typedef __attribute__((ext_vector_type(16))) float floatx16;

// ---------------- helpers ----------------
__device__ __forceinline__ ushort f2bf(float f) {
    unsigned u = __float_as_uint(f);
    unsigned r = (u + 0x7fffu + ((u >> 16) & 1u)) >> 16;   // RNE
    return (ushort)r;
}
__device__ __forceinline__ float bf2f(ushort h) {
    return __uint_as_float(((unsigned)h) << 16);
}
__device__ __forceinline__ unsigned fmap(float f) {       // monotone float->uint
    unsigned u = __float_as_uint(f);
    return (u & 0x80000000u) ? ~u : (u | 0x80000000u);
}
__device__ __forceinline__ float funmap(unsigned m) {
    return __uint_as_float((m & 0x80000000u) ? (m ^ 0x80000000u) : ~m);
}
__device__ __forceinline__ void gld16(const void* g, void* l) {
    __builtin_amdgcn_global_load_lds(
        (const __attribute__((address_space(1))) void*)g,
        (__attribute__((address_space(3))) void*)l, 16, 0, 0);
}

// ---------- fused: fp32 -> bf16 hi/lo split + row sum of squares (+packed init) ----------
// one wave per row
__global__ __launch_bounds__(256) void split_rss_k(const float* __restrict__ src,
    ushort* __restrict__ hi, ushort* __restrict__ lo, float* __restrict__ ss,
    ull* __restrict__ packed, int nrows)
{
    int gid  = blockIdx.x * blockDim.x + threadIdx.x;
    int row  = gid >> 6;
    int lane = threadIdx.x & 63;
    if (row >= nrows) return;
    const float4* r = (const float4*)(src + (size_t)row * DIM);
    ushort4* h4 = (ushort4*)(hi + (size_t)row * DIM);
    ushort4* l4 = (ushort4*)(lo + (size_t)row * DIM);
    float s = 0.f;
#pragma unroll
    for (int i = lane; i < DIM / 4; i += 64) {
        float4 v = r[i];
        s += v.x * v.x + v.y * v.y + v.z * v.z + v.w * v.w;
        ushort4 h, l;
        h.x = f2bf(v.x); l.x = f2bf(v.x - bf2f(h.x));
        h.y = f2bf(v.y); l.y = f2bf(v.y - bf2f(h.y));
        h.z = f2bf(v.z); l.z = f2bf(v.z - bf2f(h.z));
        h.w = f2bf(v.w); l.w = f2bf(v.w - bf2f(h.w));
        h4[i] = h; l4[i] = l;
    }
#pragma unroll
    for (int off = 32; off > 0; off >>= 1) s += __shfl_down(s, off, 64);
    if (lane == 0) {
        ss[row] = s;
        if (packed) packed[row] = ~0ull;   // fused init (x-pass only)
    }
}

// ---------- MFMA distance + argmin (32x32x16 bf16, 3-pass hi/lo split) ----------
// grid (128, 64): 128x128 tile of rows x codes.
// LDS cell swizzle: row r's 16B cell p holds global segment p ^ ((r>>1)&3);
// 32x32 fragment reads (cell (ks*2+(lane>>5)) ^ ((r>>1)&3)) hit all 8 bank-groups
// per 8-lane beat -> conflict-free (verified 0 conflicts with same swizzle in r4).
__global__ __launch_bounds__(256, 4) void dist_mfma_k(
    const ushort* __restrict__ xh, const ushort* __restrict__ xl,
    const ushort* __restrict__ ch, const ushort* __restrict__ cl,
    const float* __restrict__ e2, ull* __restrict__ packed)
{
    __shared__ ushort Ah[128 * 32];
    __shared__ ushort Al[128 * 32];
    __shared__ ushort Bh[128 * 32];
    __shared__ ushort Bl[128 * 32];

    const int tid  = threadIdx.x;
    const int lane = tid & 63;
    const int w    = tid >> 6;
    const int wm   = w >> 1, wn = w & 1;
    const int row0 = blockIdx.x * 128;
    const int col0 = blockIdx.y * 128;

    floatx16 acc[2][2];   // [m-tile][n-tile], 64 AGPRs total
#pragma unroll
    for (int m = 0; m < 2; ++m)
#pragma unroll
        for (int n = 0; n < 2; ++n)
#pragma unroll
            for (int i = 0; i < 16; ++i) acc[m][n][i] = 0.f;

    // staging chunk map: chunk c (0..511) -> row c>>2, LDS cell c&3 at lds off c*8;
    // global segment fetched = (c&3) ^ ((c>>3)&3)  [the swizzle]
    const int c0 = tid, c1 = tid + 256;
    const int r0c = c0 >> 2, s0c = (((c0 & 3) ^ ((c0 >> 3) & 3))) * 8;
    const int r1c = c1 >> 2, s1c = (((c1 & 3) ^ ((c1 >> 3) & 3))) * 8;
    const int ga0 = (row0 + r0c) * DIM + s0c;   // + dk
    const int ga1 = (row0 + r1c) * DIM + s1c;
    const int gb0 = (col0 + r0c) * DIM + s0c;
    const int gb1 = (col0 + r1c) * DIM + s1c;
    const int l0 = c0 * 8, l1 = c1 * 8;

    // fragment row bases + swizzle keys (row within 128-row tile)
    int abase[2], aswz[2], bbase[2], bswz[2];
#pragma unroll
    for (int t2 = 0; t2 < 2; ++t2) {
        int ra = wm * 64 + t2 * 32 + (lane & 31);
        abase[t2] = ra * 32; aswz[t2] = (ra >> 1) & 3;
        int rb = wn * 64 + t2 * 32 + (lane & 31);
        bbase[t2] = rb * 32; bswz[t2] = (rb >> 1) & 3;
    }
    const int lhalf = lane >> 5;   // which K-8 half of the K=16 fragment

    for (int kk = 0; kk < 16; ++kk) {
        const int dk = kk * 32;
        __syncthreads();
        gld16(&xh[ga0 + dk], &Ah[l0]);  gld16(&xh[ga1 + dk], &Ah[l1]);
        gld16(&xl[ga0 + dk], &Al[l0]);  gld16(&xl[ga1 + dk], &Al[l1]);
        gld16(&ch[gb0 + dk], &Bh[l0]);  gld16(&ch[gb1 + dk], &Bh[l1]);
        gld16(&cl[gb0 + dk], &Bl[l0]);  gld16(&cl[gb1 + dk], &Bl[l1]);
        __syncthreads();

#pragma unroll
        for (int ks = 0; ks < 2; ++ks) {       // two K=16 steps per BK=32
            const int q = ks * 2 + lhalf;      // logical 16B segment
            short8 ah[2], al[2], bh[2], bl[2];
#pragma unroll
            for (int mt = 0; mt < 2; ++mt) {
                const int o = abase[mt] + ((q ^ aswz[mt]) * 8);
                ah[mt] = *(const short8*)&Ah[o];
                al[mt] = *(const short8*)&Al[o];
            }
#pragma unroll
            for (int nt = 0; nt < 2; ++nt) {
                const int o = bbase[nt] + ((q ^ bswz[nt]) * 8);
                bh[nt] = *(const short8*)&Bh[o];
                bl[nt] = *(const short8*)&Bl[o];
            }
#pragma unroll
            for (int mt = 0; mt < 2; ++mt)
#pragma unroll
                for (int nt = 0; nt < 2; ++nt) {
                    acc[mt][nt] = __builtin_amdgcn_mfma_f32_32x32x16_bf16(ah[mt], bh[nt], acc[mt][nt], 0, 0, 0);
                    acc[mt][nt] = __builtin_amdgcn_mfma_f32_32x32x16_bf16(ah[mt], bl[nt], acc[mt][nt], 0, 0, 0);
                    acc[mt][nt] = __builtin_amdgcn_mfma_f32_32x32x16_bf16(al[mt], bh[nt], acc[mt][nt], 0, 0, 0);
                }
        }
    }

    // epilogue: v = e2[c] - 2*dot ; argmin, first-occurrence ties.
    // C/D layout (32x32): col = lane&31, row = (reg&3) + 8*(reg>>2) + 4*(lane>>5)
    const int cidx0 = col0 + wn * 64 + (lane & 31);        // n-tile 0
    const int cidx1 = cidx0 + 32;                          // n-tile 1
    const float e2v0 = e2[cidx0];
    const float e2v1 = e2[cidx1];
#pragma unroll
    for (int mt = 0; mt < 2; ++mt) {
#pragma unroll
        for (int i = 0; i < 16; ++i) {
            float v0 = e2v0 - 2.f * acc[mt][0][i];
            float v1 = e2v1 - 2.f * acc[mt][1][i];
            float bv = v0; int bi = cidx0;                 // ascending code order
            if (v1 < bv) { bv = v1; bi = cidx1; }
#pragma unroll
            for (int mk = 1; mk < 32; mk <<= 1) {          // 32-lane butterfly (stays in half)
                float ov = __shfl_xor(bv, mk, 64);
                int   oi = __shfl_xor(bi, mk, 64);
                if (ov < bv || (ov == bv && oi < bi)) { bv = ov; bi = oi; }
            }
            if ((lane & 31) == 0) {
                int grow = row0 + wm * 64 + mt * 32 + (i & 3) + 8 * (i >> 2) + 4 * (lane >> 5);
                ull pack = ((ull)fmap(bv) << 32) | (unsigned)bi;
                atomicMin(&packed[grow], pack);
            }
        }
    }
}

// ---------- fused merge + gather + loss partials ----------
__global__ __launch_bounds__(256) void gather_loss_k(const float* __restrict__ x,
    const float* __restrict__ cb, const ull* __restrict__ packed,
    const float* __restrict__ x2, float* __restrict__ outq,
    float* __restrict__ out_idx, float* __restrict__ out_mind,
    float* __restrict__ partials)
{
    __shared__ float ps[4];
    int gid  = blockIdx.x * blockDim.x + threadIdx.x;
    int row  = gid >> 6;
    int lane = threadIdx.x & 63;
    int w    = threadIdx.x >> 6;
    float s = 0.f;
    if (row < NROWS) {
        ull p = packed[row];                 // same-address within wave: broadcast
        int k = (int)(p & 0xffffffffull);
        if (lane == 0) {
            out_idx[row]  = (float)k;
            out_mind[row] = x2[row] + funmap((unsigned)(p >> 32));
        }
        const float4* q  = (const float4*)(cb + (size_t)k * DIM);
        const float4* xr = (const float4*)(x + (size_t)row * DIM);
        float4* o = (float4*)(outq + (size_t)row * DIM);
#pragma unroll
        for (int i = lane; i < DIM / 4; i += 64) {
            float4 qv = q[i], xv = xr[i];
            o[i] = qv;
            float dx = xv.x - qv.x, dy = xv.y - qv.y;
            float dz = xv.z - qv.z, dw = xv.w - qv.w;
            s += dx * dx + dy * dy + dz * dz + dw * dw;
        }
    }
#pragma unroll
    for (int off = 32; off > 0; off >>= 1) s += __shfl_down(s, off, 64);
    if (lane == 0) ps[w] = s;
    __syncthreads();
    if (threadIdx.x == 0) partials[blockIdx.x] = ps[0] + ps[1] + ps[2] + ps[3];
}

// ---------- final reduction of partials -> loss outputs ----------
__global__ __launch_bounds__(256) void finalize_k(const float* __restrict__ partials,
    float* __restrict__ out_loss, float* __restrict__ out_commit)
{
    __shared__ float ps[4];
    int t = threadIdx.x, lane = t & 63, w = t >> 6;
    float s = 0.f;
#pragma unroll
    for (int i = 0; i < NPART / 256; ++i) s += partials[t + 256 * i];
#pragma unroll
    for (int off = 32; off > 0; off >>= 1) s += __shfl_down(s, off, 64);
    if (lane == 0) ps[w] = s;
    __syncthreads();
    if (t == 0) {
        float tot = ps[0] + ps[1] + ps[2] + ps[3];
        *out_loss   = 0.25f * tot + tot;
        *out_commit = tot;
    }
}

// ================= fallback (fp32 path, small ws) =================
#define BM 64
#define BN 64
#define BK 32
#define KSPLIT 4
#define KPER (NUM_EMB / KSPLIT)
#define NCT (KPER / BN)

__global__ __launch_bounds__(256) void rowsumsq_k(const float* __restrict__ a,
                                                  float* __restrict__ out, int nrows)
{
    int gid  = blockIdx.x * blockDim.x + threadIdx.x;
    int row  = gid >> 6;
    int lane = threadIdx.x & 63;
    if (row >= nrows) return;
    const float4* r = (const float4*)(a + (size_t)row * DIM);
    float s = 0.f;
#pragma unroll
    for (int i = lane; i < DIM / 4; i += 64) {
        float4 v = r[i];
        s += v.x * v.x + v.y * v.y + v.z * v.z + v.w * v.w;
    }
#pragma unroll
    for (int off = 32; off > 0; off >>= 1) s += __shfl_down(s, off, 64);
    if (lane == 0) out[row] = s;
}

__global__ __launch_bounds__(256) void dist_argmin_old_k(const float* __restrict__ x,
    const float* __restrict__ cb, const float* __restrict__ e2,
    float* __restrict__ part_m, int* __restrict__ part_i)
{
    __shared__ __align__(16) float As[BK][BM + 4];
    __shared__ __align__(16) float Bs[BK][BN + 4];
    __shared__ float redv[BM][16];
    __shared__ int   redi[BM][16];

    const int row0 = blockIdx.x * BM;
    const int ks   = blockIdx.y;
    const int cbeg = ks * KPER;
    const int t    = threadIdx.x;
    const int tx   = t & 15;
    const int ty   = t >> 4;
    const int ld_d = t & 31;
    const int ld_r = t >> 5;

    float minm[4]; int mini[4];
#pragma unroll
    for (int i = 0; i < 4; ++i) { minm[i] = INFINITY; mini[i] = 0; }

    for (int ct = 0; ct < NCT; ++ct) {
        const int c0 = cbeg + ct * BN;
        float acc[4][4];
#pragma unroll
        for (int i = 0; i < 4; ++i)
#pragma unroll
            for (int j = 0; j < 4; ++j) acc[i][j] = 0.f;
        for (int dc = 0; dc < DIM; dc += BK) {
#pragma unroll
            for (int rr = 0; rr < BM; rr += 8)
                As[ld_d][ld_r + rr] = x[(size_t)(row0 + ld_r + rr) * DIM + dc + ld_d];
#pragma unroll
            for (int rr = 0; rr < BN; rr += 8)
                Bs[ld_d][ld_r + rr] = cb[(size_t)(c0 + ld_r + rr) * DIM + dc + ld_d];
            __syncthreads();
#pragma unroll
            for (int d = 0; d < BK; ++d) {
                float4 av = *(const float4*)&As[d][4 * ty];
                float4 bv = *(const float4*)&Bs[d][4 * tx];
                acc[0][0] += av.x * bv.x; acc[0][1] += av.x * bv.y;
                acc[0][2] += av.x * bv.z; acc[0][3] += av.x * bv.w;
                acc[1][0] += av.y * bv.x; acc[1][1] += av.y * bv.y;
                acc[1][2] += av.y * bv.z; acc[1][3] += av.y * bv.w;
                acc[2][0] += av.z * bv.x; acc[2][1] += av.z * bv.y;
                acc[2][2] += av.z * bv.z; acc[2][3] += av.z * bv.w;
                acc[3][0] += av.w * bv.x; acc[3][1] += av.w * bv.y;
                acc[3][2] += av.w * bv.z; acc[3][3] += av.w * bv.w;
            }
            __syncthreads();
        }
#pragma unroll
        for (int j = 0; j < 4; ++j) {
            const int c = c0 + 4 * tx + j;
            const float e = e2[c];
#pragma unroll
            for (int i = 0; i < 4; ++i) {
                float m = e - 2.f * acc[i][j];
                if (m < minm[i]) { minm[i] = m; mini[i] = c; }
            }
        }
    }
#pragma unroll
    for (int i = 0; i < 4; ++i) {
        redv[4 * ty + i][tx] = minm[i];
        redi[4 * ty + i][tx] = mini[i];
    }
    __syncthreads();
    if (t < BM) {
        float bm = INFINITY; int bi = 0;
#pragma unroll
        for (int c = 0; c < 16; ++c) {
            float v = redv[t][c];
            if (v < bm) { bm = v; bi = redi[t][c]; }
        }
        part_m[(size_t)(row0 + t) * KSPLIT + ks] = bm;
        part_i[(size_t)(row0 + t) * KSPLIT + ks] = bi;
    }
}

__global__ __launch_bounds__(256) void merge_pack_k(const float* __restrict__ part_m,
    const int* __restrict__ part_i, ull* __restrict__ packed)
{
    int row = blockIdx.x * blockDim.x + threadIdx.x;
    if (row >= NROWS) return;
    float bm = INFINITY; int bi = 0;
#pragma unroll
    for (int s = 0; s < KSPLIT; ++s) {
        float v = part_m[(size_t)row * KSPLIT + s];
        if (v < bm) { bm = v; bi = part_i[(size_t)row * KSPLIT + s]; }
    }
    packed[row] = ((ull)fmap(bm) << 32) | (unsigned)bi;
}

// ================= launch =================
extern "C" void kernel_launch(void* const* d_in, const int* in_sizes, int n_in,
                              void* d_out, int out_size, void* d_ws, size_t ws_size,
                              hipStream_t stream)
{
    const float* x  = (const float*)d_in[0];   // [16384, 512]
    const float* cb = (const float*)d_in[1];   // [8192, 512]
    float* out = (float*)d_out;

    float* outq       = out;
    float* out_loss   = out + 8388608;
    float* out_idx    = out + 8388609;
    float* out_mind   = out + 8388609 + 16384;
    float* out_commit = out + 8388609 + 2 * 16384;

    char* ws = (char*)d_ws;
    float* e2      = (float*)ws;   ws += NUM_EMB * 4;
    float* x2      = (float*)ws;   ws += NROWS * 4;
    ull*   packed  = (ull*)ws;     ws += NROWS * 8;
    float* partials= (float*)ws;   ws += NPART * 4;
    ushort* xh = (ushort*)ws;      ws += (size_t)NROWS * DIM * 2;
    ushort* xl = (ushort*)ws;      ws += (size_t)NROWS * DIM * 2;
    ushort* ch = (ushort*)ws;      ws += (size_t)NUM_EMB * DIM * 2;
    ushort* cl = (ushort*)ws;      ws += (size_t)NUM_EMB * DIM * 2;
    size_t need_fast = (size_t)(ws - (char*)d_ws);

    if (ws_size >= need_fast) {
        split_rss_k<<<NROWS / 4, 256, 0, stream>>>(x, xh, xl, x2, packed, NROWS);
        split_rss_k<<<NUM_EMB / 4, 256, 0, stream>>>(cb, ch, cl, e2, (ull*)0, NUM_EMB);
        dim3 grid(NROWS / 128, NUM_EMB / 128);
        dist_mfma_k<<<grid, 256, 0, stream>>>(xh, xl, ch, cl, e2, packed);
    } else {
        // fallback: fp32 path (small ws)
        rowsumsq_k<<<NUM_EMB / 4, 256, 0, stream>>>(cb, e2, NUM_EMB);
        rowsumsq_k<<<NROWS / 4, 256, 0, stream>>>(x, x2, NROWS);
        float* pm = (float*)((char*)d_ws + NUM_EMB * 4 + NROWS * 4 + NROWS * 8 + NPART * 4);
        int*   pi = (int*)(pm + (size_t)NROWS * KSPLIT);
        dim3 grid(NROWS / BM, KSPLIT);
        dist_argmin_old_k<<<grid, 256, 0, stream>>>(x, cb, e2, pm, pi);
        merge_pack_k<<<NROWS / 256, 256, 0, stream>>>(pm, pi, packed);
    }

    gather_loss_k<<<NROWS / 4, 256, 0, stream>>>(x, cb, packed, x2, outq,
                                                 out_idx, out_mind, partials);
    finalize_k<<<1, 256, 0, stream>>>(partials, out_loss, out_commit);
}

// Round 7
// 485.433 us; speedup vs baseline: 1.2262x; 1.2262x over previous
//
#include <hip/hip_runtime.h>
#include <hip/hip_bf16.h>
#include <math.h>

#define NUM_EMB 8192
#define DIM 512
#define NROWS 16384   // 32*512
#define NPART 4096    // gather_loss partial sums (one per block)

typedef unsigned short ushort;
typedef unsigned long long ull;
typedef __attribute__((ext_vector_type(8))) short short8;
typedef __attribute__((ext_vector_type(4))) float floatx4;

// ---------------- helpers ----------------
__device__ __forceinline__ ushort f2bf(float f) {
    unsigned u = __float_as_uint(f);
    unsigned r = (u + 0x7fffu + ((u >> 16) & 1u)) >> 16;   // RNE
    return (ushort)r;
}
__device__ __forceinline__ float bf2f(ushort h) {
    return __uint_as_float(((unsigned)h) << 16);
}
__device__ __forceinline__ unsigned fmap(float f) {       // monotone float->uint
    unsigned u = __float_as_uint(f);
    return (u & 0x80000000u) ? ~u : (u | 0x80000000u);
}
__device__ __forceinline__ float funmap(unsigned m) {
    return __uint_as_float((m & 0x80000000u) ? (m ^ 0x80000000u) : ~m);
}
__device__ __forceinline__ void gld16(const void* g, void* l) {
    __builtin_amdgcn_global_load_lds(
        (const __attribute__((address_space(1))) void*)g,
        (__attribute__((address_space(3))) void*)l, 16, 0, 0);
}

// ---------- fused split for BOTH x and cb: bf16 hi/lo + row sumsq + packed init ----------
// one wave per row; blocks cover x rows then cb rows
__global__ __launch_bounds__(256) void split_all_k(const float* __restrict__ x,
    const float* __restrict__ cb,
    ushort* __restrict__ xh, ushort* __restrict__ xl,
    ushort* __restrict__ ch, ushort* __restrict__ cl,
    float* __restrict__ x2, float* __restrict__ e2, ull* __restrict__ packed)
{
    int gid  = blockIdx.x * blockDim.x + threadIdx.x;
    int row  = gid >> 6;
    int lane = threadIdx.x & 63;
    if (row >= NROWS + NUM_EMB) return;
    const float* src; ushort* hi; ushort* lo; float* ss; int r;
    if (row < NROWS) { r = row;         src = x;  hi = xh; lo = xl; ss = x2; }
    else             { r = row - NROWS; src = cb; hi = ch; lo = cl; ss = e2; }
    const float4* rp = (const float4*)(src + (size_t)r * DIM);
    ushort4* h4 = (ushort4*)(hi + (size_t)r * DIM);
    ushort4* l4 = (ushort4*)(lo + (size_t)r * DIM);
    float s = 0.f;
#pragma unroll
    for (int i = lane; i < DIM / 4; i += 64) {
        float4 v = rp[i];
        s += v.x * v.x + v.y * v.y + v.z * v.z + v.w * v.w;
        ushort4 h, l;
        h.x = f2bf(v.x); l.x = f2bf(v.x - bf2f(h.x));
        h.y = f2bf(v.y); l.y = f2bf(v.y - bf2f(h.y));
        h.z = f2bf(v.z); l.z = f2bf(v.z - bf2f(h.z));
        h.w = f2bf(v.w); l.w = f2bf(v.w - bf2f(h.w));
        h4[i] = h; l4[i] = l;
    }
#pragma unroll
    for (int off = 32; off > 0; off >>= 1) s += __shfl_down(s, off, 64);
    if (lane == 0) {
        ss[r] = s;
        if (row < NROWS) packed[row] = ~0ull;
    }
}

// ---------- MFMA distance + argmin (16x16x32 bf16, 3-pass hi/lo split) ----------
// grid (128, 64): 128x128 tile of rows x codes.
// 3-phase K-loop: [barrier; ds_read frags->regs; barrier; prefetch-gld kk+1; MFMA]
// so the global_load_lds DMA lands under the MFMA block instead of stalling at
// a vmcnt(0) barrier drain (the m97-class ~25% stall).
// LDS cell swizzle (R4, measured 0 conflicts): row r's 16B cell p holds
// global segment p ^ ((r>>1)&3); fragment reads compensate.
__global__ __launch_bounds__(256, 3) void dist_mfma_k(
    const ushort* __restrict__ xh, const ushort* __restrict__ xl,
    const ushort* __restrict__ ch, const ushort* __restrict__ cl,
    const float* __restrict__ e2, ull* __restrict__ packed)
{
    __shared__ ushort Ah[128 * 32];
    __shared__ ushort Al[128 * 32];
    __shared__ ushort Bh[128 * 32];
    __shared__ ushort Bl[128 * 32];

    const int tid  = threadIdx.x;
    const int lane = tid & 63;
    const int w    = tid >> 6;
    const int wm   = w >> 1, wn = w & 1;
    const int row0 = blockIdx.x * 128;
    const int col0 = blockIdx.y * 128;

    floatx4 acc[4][4];
#pragma unroll
    for (int m = 0; m < 4; ++m)
#pragma unroll
        for (int n = 0; n < 4; ++n) acc[m][n] = (floatx4){0.f, 0.f, 0.f, 0.f};

    // staging chunk map: chunk c (0..511) -> row c>>2, LDS cell c&3 at lds off c*8;
    // global segment fetched = (c&3) ^ ((c>>3)&3)  [the swizzle]
    const int c0 = tid, c1 = tid + 256;
    const int r0c = c0 >> 2, s0c = (((c0 & 3) ^ ((c0 >> 3) & 3))) * 8;
    const int r1c = c1 >> 2, s1c = (((c1 & 3) ^ ((c1 >> 3) & 3))) * 8;
    const int ga0 = (row0 + r0c) * DIM + s0c;   // + dk
    const int ga1 = (row0 + r1c) * DIM + s1c;
    const int gb0 = (col0 + r0c) * DIM + s0c;
    const int gb1 = (col0 + r1c) * DIM + s1c;
    const int l0 = c0 * 8, l1 = c1 * 8;

    // fragment base: row (lane&15), cell (lane>>4) ^ ((lane>>1)&3)
    const int fr = (lane & 15) * 32 + (((lane >> 4) ^ ((lane >> 1) & 3)) * 8);

    // prologue: stage tile kk=0
    gld16(&xh[ga0], &Ah[l0]);  gld16(&xh[ga1], &Ah[l1]);
    gld16(&xl[ga0], &Al[l0]);  gld16(&xl[ga1], &Al[l1]);
    gld16(&ch[gb0], &Bh[l0]);  gld16(&ch[gb1], &Bh[l1]);
    gld16(&cl[gb0], &Bl[l0]);  gld16(&cl[gb1], &Bl[l1]);

    for (int kk = 0; kk < 16; ++kk) {
        __syncthreads();   // drains this tile's DMA (landed under previous MFMA block)

        short8 ah[4], al[4], bh[4], bl[4];
#pragma unroll
        for (int m = 0; m < 4; ++m) {
            const int o = (wm * 64 + m * 16) * 32 + fr;
            ah[m] = *(const short8*)&Ah[o];
            al[m] = *(const short8*)&Al[o];
        }
#pragma unroll
        for (int n = 0; n < 4; ++n) {
            const int o = (wn * 64 + n * 16) * 32 + fr;
            bh[n] = *(const short8*)&Bh[o];
            bl[n] = *(const short8*)&Bl[o];
        }
        __syncthreads();   // all waves done reading LDS -> safe to overwrite

        if (kk != 15) {    // prefetch next tile; overlaps the MFMA block below
            const int dk = (kk + 1) * 32;
            gld16(&xh[ga0 + dk], &Ah[l0]);  gld16(&xh[ga1 + dk], &Ah[l1]);
            gld16(&xl[ga0 + dk], &Al[l0]);  gld16(&xl[ga1 + dk], &Al[l1]);
            gld16(&ch[gb0 + dk], &Bh[l0]);  gld16(&ch[gb1 + dk], &Bh[l1]);
            gld16(&cl[gb0 + dk], &Bl[l0]);  gld16(&cl[gb1 + dk], &Bl[l1]);
        }

#pragma unroll
        for (int m = 0; m < 4; ++m)
#pragma unroll
            for (int n = 0; n < 4; ++n) {
                acc[m][n] = __builtin_amdgcn_mfma_f32_16x16x32_bf16(ah[m], bh[n], acc[m][n], 0, 0, 0);
                acc[m][n] = __builtin_amdgcn_mfma_f32_16x16x32_bf16(ah[m], bl[n], acc[m][n], 0, 0, 0);
                acc[m][n] = __builtin_amdgcn_mfma_f32_16x16x32_bf16(al[m], bh[n], acc[m][n], 0, 0, 0);
            }
    }

    // epilogue: v = e2[c] - 2*dot ; argmin with first-occurrence tie-break
    float e2v[4];
    int   cidx[4];
#pragma unroll
    for (int n = 0; n < 4; ++n) {
        cidx[n] = col0 + wn * 64 + n * 16 + (lane & 15);
        e2v[n]  = e2[cidx[n]];
    }
#pragma unroll
    for (int m = 0; m < 4; ++m) {
#pragma unroll
        for (int r = 0; r < 4; ++r) {
            float bv = INFINITY; int bi = 0x7fffffff;
#pragma unroll
            for (int n = 0; n < 4; ++n) {        // ascending code order
                float v = e2v[n] - 2.f * acc[m][n][r];
                if (v < bv) { bv = v; bi = cidx[n]; }
            }
#pragma unroll
            for (int mk = 1; mk < 16; mk <<= 1) {  // 16-lane butterfly (same quad group)
                float ov = __shfl_xor(bv, mk, 64);
                int   oi = __shfl_xor(bi, mk, 64);
                if (ov < bv || (ov == bv && oi < bi)) { bv = ov; bi = oi; }
            }
            if ((lane & 15) == 0) {
                int grow = row0 + wm * 64 + m * 16 + (lane >> 4) * 4 + r;
                ull pack = ((ull)fmap(bv) << 32) | (unsigned)bi;
                atomicMin(&packed[grow], pack);
            }
        }
    }
}

// ---------- fused merge + gather + loss partials ----------
__global__ __launch_bounds__(256) void gather_loss_k(const float* __restrict__ x,
    const float* __restrict__ cb, const ull* __restrict__ packed,
    const float* __restrict__ x2, float* __restrict__ outq,
    float* __restrict__ out_idx, float* __restrict__ out_mind,
    float* __restrict__ partials)
{
    __shared__ float ps[4];
    int gid  = blockIdx.x * blockDim.x + threadIdx.x;
    int row  = gid >> 6;
    int lane = threadIdx.x & 63;
    int w    = threadIdx.x >> 6;
    float s = 0.f;
    if (row < NROWS) {
        ull p = packed[row];                 // same-address within wave: broadcast
        int k = (int)(p & 0xffffffffull);
        if (lane == 0) {
            out_idx[row]  = (float)k;
            out_mind[row] = x2[row] + funmap((unsigned)(p >> 32));
        }
        const float4* q  = (const float4*)(cb + (size_t)k * DIM);
        const float4* xr = (const float4*)(x + (size_t)row * DIM);
        float4* o = (float4*)(outq + (size_t)row * DIM);
#pragma unroll
        for (int i = lane; i < DIM / 4; i += 64) {
            float4 qv = q[i], xv = xr[i];
            o[i] = qv;
            float dx = xv.x - qv.x, dy = xv.y - qv.y;
            float dz = xv.z - qv.z, dw = xv.w - qv.w;
            s += dx * dx + dy * dy + dz * dz + dw * dw;
        }
    }
#pragma unroll
    for (int off = 32; off > 0; off >>= 1) s += __shfl_down(s, off, 64);
    if (lane == 0) ps[w] = s;
    __syncthreads();
    if (threadIdx.x == 0) partials[blockIdx.x] = ps[0] + ps[1] + ps[2] + ps[3];
}

// ---------- final reduction of partials -> loss outputs ----------
__global__ __launch_bounds__(256) void finalize_k(const float* __restrict__ partials,
    float* __restrict__ out_loss, float* __restrict__ out_commit)
{
    __shared__ float ps[4];
    int t = threadIdx.x, lane = t & 63, w = t >> 6;
    float s = 0.f;
#pragma unroll
    for (int i = 0; i < NPART / 256; ++i) s += partials[t + 256 * i];
#pragma unroll
    for (int off = 32; off > 0; off >>= 1) s += __shfl_down(s, off, 64);
    if (lane == 0) ps[w] = s;
    __syncthreads();
    if (t == 0) {
        float tot = ps[0] + ps[1] + ps[2] + ps[3];
        *out_loss   = 0.25f * tot + tot;
        *out_commit = tot;
    }
}

// ================= fallback (fp32 path, small ws) =================
#define BM 64
#define BN 64
#define BK 32
#define KSPLIT 4
#define KPER (NUM_EMB / KSPLIT)
#define NCT (KPER / BN)

__global__ __launch_bounds__(256) void rowsumsq_k(const float* __restrict__ a,
                                                  float* __restrict__ out, int nrows)
{
    int gid  = blockIdx.x * blockDim.x + threadIdx.x;
    int row  = gid >> 6;
    int lane = threadIdx.x & 63;
    if (row >= nrows) return;
    const float4* r = (const float4*)(a + (size_t)row * DIM);
    float s = 0.f;
#pragma unroll
    for (int i = lane; i < DIM / 4; i += 64) {
        float4 v = r[i];
        s += v.x * v.x + v.y * v.y + v.z * v.z + v.w * v.w;
    }
#pragma unroll
    for (int off = 32; off > 0; off >>= 1) s += __shfl_down(s, off, 64);
    if (lane == 0) out[row] = s;
}

__global__ __launch_bounds__(256) void dist_argmin_old_k(const float* __restrict__ x,
    const float* __restrict__ cb, const float* __restrict__ e2,
    float* __restrict__ part_m, int* __restrict__ part_i)
{
    __shared__ __align__(16) float As[BK][BM + 4];
    __shared__ __align__(16) float Bs[BK][BN + 4];
    __shared__ float redv[BM][16];
    __shared__ int   redi[BM][16];

    const int row0 = blockIdx.x * BM;
    const int ks   = blockIdx.y;
    const int cbeg = ks * KPER;
    const int t    = threadIdx.x;
    const int tx   = t & 15;
    const int ty   = t >> 4;
    const int ld_d = t & 31;
    const int ld_r = t >> 5;

    float minm[4]; int mini[4];
#pragma unroll
    for (int i = 0; i < 4; ++i) { minm[i] = INFINITY; mini[i] = 0; }

    for (int ct = 0; ct < NCT; ++ct) {
        const int c0 = cbeg + ct * BN;
        float acc[4][4];
#pragma unroll
        for (int i = 0; i < 4; ++i)
#pragma unroll
            for (int j = 0; j < 4; ++j) acc[i][j] = 0.f;
        for (int dc = 0; dc < DIM; dc += BK) {
#pragma unroll
            for (int rr = 0; rr < BM; rr += 8)
                As[ld_d][ld_r + rr] = x[(size_t)(row0 + ld_r + rr) * DIM + dc + ld_d];
#pragma unroll
            for (int rr = 0; rr < BN; rr += 8)
                Bs[ld_d][ld_r + rr] = cb[(size_t)(c0 + ld_r + rr) * DIM + dc + ld_d];
            __syncthreads();
#pragma unroll
            for (int d = 0; d < BK; ++d) {
                float4 av = *(const float4*)&As[d][4 * ty];
                float4 bv = *(const float4*)&Bs[d][4 * tx];
                acc[0][0] += av.x * bv.x; acc[0][1] += av.x * bv.y;
                acc[0][2] += av.x * bv.z; acc[0][3] += av.x * bv.w;
                acc[1][0] += av.y * bv.x; acc[1][1] += av.y * bv.y;
                acc[1][2] += av.y * bv.z; acc[1][3] += av.y * bv.w;
                acc[2][0] += av.z * bv.x; acc[2][1] += av.z * bv.y;
                acc[2][2] += av.z * bv.z; acc[2][3] += av.z * bv.w;
                acc[3][0] += av.w * bv.x; acc[3][1] += av.w * bv.y;
                acc[3][2] += av.w * bv.z; acc[3][3] += av.w * bv.w;
            }
            __syncthreads();
        }
#pragma unroll
        for (int j = 0; j < 4; ++j) {
            const int c = c0 + 4 * tx + j;
            const float e = e2[c];
#pragma unroll
            for (int i = 0; i < 4; ++i) {
                float m = e - 2.f * acc[i][j];
                if (m < minm[i]) { minm[i] = m; mini[i] = c; }
            }
        }
    }
#pragma unroll
    for (int i = 0; i < 4; ++i) {
        redv[4 * ty + i][tx] = minm[i];
        redi[4 * ty + i][tx] = mini[i];
    }
    __syncthreads();
    if (t < BM) {
        float bm = INFINITY; int bi = 0;
#pragma unroll
        for (int c = 0; c < 16; ++c) {
            float v = redv[t][c];
            if (v < bm) { bm = v; bi = redi[t][c]; }
        }
        part_m[(size_t)(row0 + t) * KSPLIT + ks] = bm;
        part_i[(size_t)(row0 + t) * KSPLIT + ks] = bi;
    }
}

__global__ __launch_bounds__(256) void merge_pack_k(const float* __restrict__ part_m,
    const int* __restrict__ part_i, ull* __restrict__ packed)
{
    int row = blockIdx.x * blockDim.x + threadIdx.x;
    if (row >= NROWS) return;
    float bm = INFINITY; int bi = 0;
#pragma unroll
    for (int s = 0; s < KSPLIT; ++s) {
        float v = part_m[(size_t)row * KSPLIT + s];
        if (v < bm) { bm = v; bi = part_i[(size_t)row * KSPLIT + s]; }
    }
    packed[row] = ((ull)fmap(bm) << 32) | (unsigned)bi;
}

// ================= launch =================
extern "C" void kernel_launch(void* const* d_in, const int* in_sizes, int n_in,
                              void* d_out, int out_size, void* d_ws, size_t ws_size,
                              hipStream_t stream)
{
    const float* x  = (const float*)d_in[0];   // [16384, 512]
    const float* cb = (const float*)d_in[1];   // [8192, 512]
    float* out = (float*)d_out;

    float* outq       = out;
    float* out_loss   = out + 8388608;
    float* out_idx    = out + 8388609;
    float* out_mind   = out + 8388609 + 16384;
    float* out_commit = out + 8388609 + 2 * 16384;

    char* ws = (char*)d_ws;
    float* e2      = (float*)ws;   ws += NUM_EMB * 4;
    float* x2      = (float*)ws;   ws += NROWS * 4;
    ull*   packed  = (ull*)ws;     ws += NROWS * 8;
    float* partials= (float*)ws;   ws += NPART * 4;
    ushort* xh = (ushort*)ws;      ws += (size_t)NROWS * DIM * 2;
    ushort* xl = (ushort*)ws;      ws += (size_t)NROWS * DIM * 2;
    ushort* ch = (ushort*)ws;      ws += (size_t)NUM_EMB * DIM * 2;
    ushort* cl = (ushort*)ws;      ws += (size_t)NUM_EMB * DIM * 2;
    size_t need_fast = (size_t)(ws - (char*)d_ws);

    if (ws_size >= need_fast) {
        split_all_k<<<(NROWS + NUM_EMB) / 4, 256, 0, stream>>>(x, cb, xh, xl, ch, cl,
                                                               x2, e2, packed);
        dim3 grid(NROWS / 128, NUM_EMB / 128);
        dist_mfma_k<<<grid, 256, 0, stream>>>(xh, xl, ch, cl, e2, packed);
    } else {
        // fallback: fp32 path (small ws)
        rowsumsq_k<<<NUM_EMB / 4, 256, 0, stream>>>(cb, e2, NUM_EMB);
        rowsumsq_k<<<NROWS / 4, 256, 0, stream>>>(x, x2, NROWS);
        float* pm = (float*)((char*)d_ws + NUM_EMB * 4 + NROWS * 4 + NROWS * 8 + NPART * 4);
        int*   pi = (int*)(pm + (size_t)NROWS * KSPLIT);
        dim3 grid(NROWS / BM, KSPLIT);
        dist_argmin_old_k<<<grid, 256, 0, stream>>>(x, cb, e2, pm, pi);
        merge_pack_k<<<NROWS / 256, 256, 0, stream>>>(pm, pi, packed);
    }

    gather_loss_k<<<NROWS / 4, 256, 0, stream>>>(x, cb, packed, x2, outq,
                                                 out_idx, out_mind, partials);
    finalize_k<<<1, 256, 0, stream>>>(partials, out_loss, out_commit);
}